// Round 1
// baseline (387.612 us; speedup 1.0000x reference)
//
#include <hip/hip_runtime.h>
#include <hip/hip_bf16.h>

typedef unsigned short u16;
typedef __attribute__((ext_vector_type(8))) short bf16x8;
typedef __attribute__((ext_vector_type(8))) unsigned short u16x8;
typedef __attribute__((ext_vector_type(4))) unsigned short u16x4;
typedef __attribute__((ext_vector_type(4))) float f32x4;

#define DEVI __device__ __forceinline__

static constexpr int Bn = 8, Tn = 1024, Fn = 1024, Hn = 16, DKn = 64;
static constexpr int Mtot = Bn * Tn;  // 8192

DEVI u16 f2bf(float x) {
  unsigned u = __builtin_bit_cast(unsigned, x);
  u += 0x7fffu + ((u >> 16) & 1u);
  return (u16)(u >> 16);
}

DEVI f32x4 mfma16(bf16x8 a, bf16x8 b, f32x4 c) {
  return __builtin_amdgcn_mfma_f32_16x16x32_bf16(a, b, c, 0, 0, 0);
}

typedef const __attribute__((address_space(1))) void GAS;
typedef __attribute__((address_space(3))) void LAS;
#define GLL16(gp, lp) __builtin_amdgcn_global_load_lds((GAS*)(gp), (LAS*)(lp), 16, 0, 0)

// ---------------- fp32 -> bf16 conversion ----------------
__global__ __launch_bounds__(256) void cvt_f32_bf16(const float* __restrict__ in,
                                                    u16* __restrict__ out, int n) {
  int i = (blockIdx.x * 256 + threadIdx.x) * 8;
  if (i >= n) return;
  const float4* p = reinterpret_cast<const float4*>(in + i);
  float4 a = p[0], b = p[1];
  float v[8] = {a.x, a.y, a.z, a.w, b.x, b.y, b.z, b.w};
  u16x8 r;
#pragma unroll
  for (int j = 0; j < 8; j++) r[j] = f2bf(v[j]);
  *reinterpret_cast<u16x8*>(out + i) = r;
}

// ---------------- GEMM  C[M,N] = A[M,K] * W[N,K]^T + bias ----------------
// MODE 0: write bf16 (B,H,T,DK)  (Q/K proj)
// MODE 1: write bf16 (B,H,DK,T)  (V proj, transposed)
// MODE 2: write fp32 (M,N) = (acc+bias)*mask[m]  (out proj)
template <int MODE>
__global__ __launch_bounds__(256) void gemm_bt(const u16* __restrict__ A,
                                               const u16* __restrict__ Bw,
                                               const float* __restrict__ bias,
                                               const float* __restrict__ mask,
                                               u16* __restrict__ Obf,
                                               float* __restrict__ Of) {
  constexpr int Kd = 1024;
  __shared__ u16 sA[2][128 * 32];
  __shared__ u16 sB[2][128 * 32];
  const int tid = threadIdx.x;
  const int l = tid & 63, w = tid >> 6;
  const int m0 = blockIdx.x * 128;  // 64 tiles
  const int n0 = blockIdx.y * 128;  // 8 tiles
  const int srow = l >> 2, sslot = l & 3;
  const int wr = w >> 1, wc = w & 1;
  const int lr = l & 15, g = l >> 4;

  f32x4 acc[4][4];
#pragma unroll
  for (int i = 0; i < 4; i++)
#pragma unroll
    for (int j = 0; j < 4; j++) acc[i][j] = f32x4{0.f, 0.f, 0.f, 0.f};

  auto stage = [&](int bf, int kt) {
    const u16* Ab = A + (size_t)m0 * Kd + kt * 32;
    const u16* Bb = Bw + (size_t)n0 * Kd + kt * 32;
#pragma unroll
    for (int i = 0; i < 2; i++) {
      int row = i * 64 + w * 16 + srow;
      GLL16(Ab + (size_t)row * Kd + sslot * 8, &sA[bf][i * 2048 + w * 512]);
      GLL16(Bb + (size_t)row * Kd + sslot * 8, &sB[bf][i * 2048 + w * 512]);
    }
  };

  stage(0, 0);
  __syncthreads();
  int cur = 0;
  for (int kt = 0; kt < 32; ++kt) {
    if (kt + 1 < 32) stage(cur ^ 1, kt + 1);
    bf16x8 af[4], bfr[4];
#pragma unroll
    for (int mi = 0; mi < 4; mi++)
      af[mi] = *reinterpret_cast<const bf16x8*>(&sA[cur][(wr * 64 + mi * 16 + lr) * 32 + g * 8]);
#pragma unroll
    for (int ni = 0; ni < 4; ni++)
      bfr[ni] = *reinterpret_cast<const bf16x8*>(&sB[cur][(wc * 64 + ni * 16 + lr) * 32 + g * 8]);
#pragma unroll
    for (int mi = 0; mi < 4; mi++)
#pragma unroll
      for (int ni = 0; ni < 4; ni++) acc[mi][ni] = mfma16(af[mi], bfr[ni], acc[mi][ni]);
    __syncthreads();
    cur ^= 1;
  }

  // epilogue
  int ncol[4];
  float bv[4];
#pragma unroll
  for (int ni = 0; ni < 4; ni++) {
    ncol[ni] = n0 + wc * 64 + ni * 16 + lr;
    bv[ni] = bias[ncol[ni]];
  }
#pragma unroll
  for (int mi = 0; mi < 4; mi++) {
    const int mb = m0 + wr * 64 + mi * 16 + g * 4;
    if constexpr (MODE == 1) {
      // V^T: t consecutive in j -> pack 4 bf16 per store
#pragma unroll
      for (int ni = 0; ni < 4; ni++) {
        const int n = ncol[ni];
        const int h = n >> 6, dk = n & 63;
        u16x4 pk;
#pragma unroll
        for (int j = 0; j < 4; j++) pk[j] = f2bf(acc[mi][ni][j] + bv[ni]);
        const int b = mb >> 10, t = mb & 1023;
        size_t idx = (((size_t)b * 16 + h) * 64 + dk) * 1024 + t;
        *reinterpret_cast<u16x4*>(Obf + idx) = pk;
      }
    } else {
#pragma unroll
      for (int j = 0; j < 4; j++) {
        const int m = mb + j;
        const int b = m >> 10, t = m & 1023;
        float mk = 0.f;
        if constexpr (MODE == 2) mk = mask[m];
#pragma unroll
        for (int ni = 0; ni < 4; ni++) {
          const int n = ncol[ni];
          float v = acc[mi][ni][j] + bv[ni];
          if constexpr (MODE == 0) {
            const int h = n >> 6, dk = n & 63;
            Obf[((((size_t)b * 16 + h) * 1024 + t) * 64) + dk] = f2bf(v);
          } else {
            Of[(size_t)m * 1024 + n] = v * mk;
          }
        }
      }
    }
  }
}

// ---------------- flash attention ----------------
// grid: 2048 blocks (bh = blk>>4, qtile = blk&15); 256 thr = 4 indep waves x 16 q-rows
__global__ __launch_bounds__(256) void flash_attn(const u16* __restrict__ Qb,
                                                  const u16* __restrict__ Kb,
                                                  const u16* __restrict__ Vt,
                                                  u16* __restrict__ ctx) {
  __shared__ u16 pbuf[4][16 * 64];
  const int tid = threadIdx.x, l = tid & 63, w = tid >> 6;
  const int lr = l & 15, g = l >> 4;
  const int qt = blockIdx.x & 15, bh = blockIdx.x >> 4;
  const u16* Qh = Qb + (size_t)bh * (Tn * DKn);
  const u16* Kh = Kb + (size_t)bh * (Tn * DKn);
  const u16* Vh = Vt + (size_t)bh * (Tn * DKn);

  bf16x8 aq[2];
  {
    const int qrow = qt * 64 + w * 16 + lr;
    aq[0] = *reinterpret_cast<const bf16x8*>(Qh + (size_t)qrow * 64 + g * 8);
    aq[1] = *reinterpret_cast<const bf16x8*>(Qh + (size_t)qrow * 64 + 32 + g * 8);
  }
  float mrow[4], lsum[4];
  f32x4 of[4];
#pragma unroll
  for (int j = 0; j < 4; j++) { mrow[j] = -1e30f; lsum[j] = 0.f; }
#pragma unroll
  for (int c = 0; c < 4; c++) of[c] = f32x4{0.f, 0.f, 0.f, 0.f};

  char* pb = (char*)&pbuf[w][0];
  const float SC = 0.125f * 1.44269504089f;  // 1/sqrt(DK) * log2(e)

  for (int kv0 = 0; kv0 < Tn; kv0 += 64) {
    // S = Q K^T (scaled into exp2 domain)
    f32x4 sf[4];
#pragma unroll
    for (int c = 0; c < 4; c++) {
      const u16* kr = Kh + (size_t)(kv0 + c * 16 + lr) * 64;
      bf16x8 b0 = *reinterpret_cast<const bf16x8*>(kr + g * 8);
      bf16x8 b1 = *reinterpret_cast<const bf16x8*>(kr + 32 + g * 8);
      f32x4 z = f32x4{0.f, 0.f, 0.f, 0.f};
      z = mfma16(aq[0], b0, z);
      z = mfma16(aq[1], b1, z);
      sf[c] = z;
    }
#pragma unroll
    for (int c = 0; c < 4; c++)
#pragma unroll
      for (int j = 0; j < 4; j++) sf[c][j] *= SC;

    float alpha[4];
#pragma unroll
    for (int j = 0; j < 4; j++) {
      float mx = fmaxf(fmaxf(sf[0][j], sf[1][j]), fmaxf(sf[2][j], sf[3][j]));
      mx = fmaxf(mx, __shfl_xor(mx, 1));
      mx = fmaxf(mx, __shfl_xor(mx, 2));
      mx = fmaxf(mx, __shfl_xor(mx, 4));
      mx = fmaxf(mx, __shfl_xor(mx, 8));
      const float mn = fmaxf(mrow[j], mx);
      alpha[j] = exp2f(mrow[j] - mn);
      mrow[j] = mn;
      float rs = 0.f;
#pragma unroll
      for (int c = 0; c < 4; c++) {
        float p = exp2f(sf[c][j] - mn);
        sf[c][j] = p;
        rs += p;
      }
      rs += __shfl_xor(rs, 1);
      rs += __shfl_xor(rs, 2);
      rs += __shfl_xor(rs, 4);
      rs += __shfl_xor(rs, 8);
      lsum[j] = lsum[j] * alpha[j] + rs;
    }
#pragma unroll
    for (int c = 0; c < 4; c++)
#pragma unroll
      for (int j = 0; j < 4; j++) of[c][j] *= alpha[j];

    // P -> LDS (bf16, XOR-swizzled rows: conflict-free b128 re-read)
#pragma unroll
    for (int c = 0; c < 4; c++)
#pragma unroll
      for (int j = 0; j < 4; j++) {
        const int row = g * 4 + j, col = c * 16 + lr;
        int byte = (row * 128 + col * 2) ^ ((row & 7) << 4);
        *reinterpret_cast<u16*>(pb + byte) = f2bf(sf[c][j]);
      }
    bf16x8 ap[2];
    {
      const int b0 = (lr * 128 + g * 16) ^ ((lr & 7) << 4);
      const int b1 = (lr * 128 + 64 + g * 16) ^ ((lr & 7) << 4);
      ap[0] = *reinterpret_cast<const bf16x8*>(pb + b0);
      ap[1] = *reinterpret_cast<const bf16x8*>(pb + b1);
    }
    // O += P V  (V^T rows are contiguous in kv)
#pragma unroll
    for (int c2 = 0; c2 < 4; c2++) {
      const u16* vr = Vh + (size_t)(c2 * 16 + lr) * 1024 + kv0;
      bf16x8 v0 = *reinterpret_cast<const bf16x8*>(vr + g * 8);
      bf16x8 v1 = *reinterpret_cast<const bf16x8*>(vr + 32 + g * 8);
      of[c2] = mfma16(ap[0], v0, of[c2]);
      of[c2] = mfma16(ap[1], v1, of[c2]);
    }
  }

  // epilogue: ctx (B*T, F) bf16
  const int b = bh >> 4, h = bh & 15;
#pragma unroll
  for (int j = 0; j < 4; j++) {
    const float inv = 1.0f / lsum[j];
    const int qrow = qt * 64 + w * 16 + g * 4 + j;
    const size_t base = ((size_t)b * 1024 + qrow) * 1024 + h * 64;
#pragma unroll
    for (int c2 = 0; c2 < 4; c2++) ctx[base + c2 * 16 + lr] = f2bf(of[c2][j] * inv);
  }
}

// ---------------- launch ----------------
extern "C" void kernel_launch(void* const* d_in, const int* in_sizes, int n_in,
                              void* d_out, int out_size, void* d_ws, size_t ws_size,
                              hipStream_t stream) {
  const float* query = (const float*)d_in[0];
  const float* key = (const float*)d_in[1];
  const float* value = (const float*)d_in[2];
  const float* mask = (const float*)d_in[3];
  const float* Wq = (const float*)d_in[4];
  const float* bq = (const float*)d_in[5];
  const float* Wk = (const float*)d_in[6];
  const float* bk = (const float*)d_in[7];
  const float* Wv = (const float*)d_in[8];
  const float* bv = (const float*)d_in[9];
  const float* Wo = (const float*)d_in[10];
  const float* bo = (const float*)d_in[11];
  (void)in_sizes; (void)n_in; (void)out_size; (void)ws_size;

  u16* ws = (u16*)d_ws;
  const size_t MB8 = (size_t)8 << 20;  // 8M u16 = 16 MB
  u16* Xq = ws;                        // reused as ctx after Q-proj
  u16* Xk = ws + MB8;
  u16* Xv = ws + 2 * MB8;
  u16* Wqb = ws + 3 * MB8;
  u16* Wkb = Wqb + (1 << 20);
  u16* Wvb = Wkb + (1 << 20);
  u16* Wob = Wvb + (1 << 20);
  u16* Qb = Wob + (1 << 20);
  u16* Kb = Qb + MB8;
  u16* Vtb = Kb + MB8;
  u16* ctx = Xq;

  const int NX = Mtot * Fn;  // 8388608
  const int NW = Fn * Fn;    // 1048576
  cvt_f32_bf16<<<NX / (8 * 256), 256, 0, stream>>>(query, Xq, NX);
  cvt_f32_bf16<<<NX / (8 * 256), 256, 0, stream>>>(key, Xk, NX);
  cvt_f32_bf16<<<NX / (8 * 256), 256, 0, stream>>>(value, Xv, NX);
  cvt_f32_bf16<<<NW / (8 * 256), 256, 0, stream>>>(Wq, Wqb, NW);
  cvt_f32_bf16<<<NW / (8 * 256), 256, 0, stream>>>(Wk, Wkb, NW);
  cvt_f32_bf16<<<NW / (8 * 256), 256, 0, stream>>>(Wv, Wvb, NW);
  cvt_f32_bf16<<<NW / (8 * 256), 256, 0, stream>>>(Wo, Wob, NW);

  dim3 gg(Mtot / 128, Fn / 128);
  gemm_bt<0><<<gg, 256, 0, stream>>>(Xq, Wqb, bq, nullptr, Qb, nullptr);
  gemm_bt<0><<<gg, 256, 0, stream>>>(Xk, Wkb, bk, nullptr, Kb, nullptr);
  gemm_bt<1><<<gg, 256, 0, stream>>>(Xv, Wvb, bv, nullptr, Vtb, nullptr);

  flash_attn<<<Bn * Hn * (Tn / 64), 256, 0, stream>>>(Qb, Kb, Vtb, ctx);

  gemm_bt<2><<<gg, 256, 0, stream>>>(ctx, Wob, bo, mask, nullptr, (float*)d_out);
}